// Round 12
// baseline (1177.330 us; speedup 1.0000x reference)
//
#include <hip/hip_runtime.h>
#include <cstdint>
#include <cstddef>

// ---- problem constants ----
#define D_IN   2048
#define STATE_N 16
#define SEQ_L  4096
#define BATCH  4
#define M_TOT  (BATCH * SEQ_L)   // 16384
#define NCAT   (3 * D_IN)        // 6144
#define LC     128               // scan chunk length
#define NCHUNK (SEQ_L / LC)      // 32
#define BDN    (BATCH * D_IN * STATE_N)  // 131072
#define BD     (BATCH * D_IN)            // 8192

// GEMM tile params: 128x128 tile (m97 structure), BK=64, single-buffer LDS 32KB,
// 256 thr / 4 waves; ks-inner fragment reads keep VGPR ~90 -> 4-5 blocks/CU.
#define BK     64

typedef __bf16 bf16x8 __attribute__((ext_vector_type(8)));
typedef float  f32x4  __attribute__((ext_vector_type(4)));
typedef unsigned int u32x4 __attribute__((ext_vector_type(4)));

__device__ __forceinline__ float softplus_f(float x) {
    return log1pf(expf(-fabsf(x))) + fmaxf(x, 0.f);
}
__device__ __forceinline__ unsigned short f2bf(float f) {  // RNE f32->bf16
    unsigned u = __float_as_uint(f);
    u += 0x7FFFu + ((u >> 16) & 1u);
    return (unsigned short)(u >> 16);
}
__device__ __forceinline__ float bf2f(unsigned short h) {
    return __uint_as_float(((unsigned)h) << 16);
}

// async global->LDS, 16B per lane (wave-uniform LDS base + lane*16 pattern)
__device__ __forceinline__ void gload_lds16(const unsigned short* g, unsigned short* l) {
    __builtin_amdgcn_global_load_lds(
        (const __attribute__((address_space(1))) unsigned int*)(const void*)g,
        (__attribute__((address_space(3))) unsigned int*)(void*)l,
        16, 0, 0);
}

// ---------------- u -> bf16 ----------------
__global__ __launch_bounds__(256) void k_cvt_u(const float* __restrict__ u,
                                               unsigned short* __restrict__ ub) {
    size_t i = ((size_t)blockIdx.x * 256 + threadIdx.x) * 8;
    f32x4 a = *(const f32x4*)(u + i);
    f32x4 b = *(const f32x4*)(u + i + 4);
    u32x4 o;
    o[0] = (unsigned)f2bf(a[0]) | ((unsigned)f2bf(a[1]) << 16);
    o[1] = (unsigned)f2bf(a[2]) | ((unsigned)f2bf(a[3]) << 16);
    o[2] = (unsigned)f2bf(b[0]) | ((unsigned)f2bf(b[1]) << 16);
    o[3] = (unsigned)f2bf(b[2]) | ((unsigned)f2bf(b[3]) << 16);
    *(u32x4*)(ub + i) = o;
}

// ---------------- W(cat) -> Wt bf16 (NCAT x K) ----------------
__global__ __launch_bounds__(256) void k_transpose(const float* __restrict__ Wdt,
                                                   const float* __restrict__ Wb,
                                                   const float* __restrict__ Wc,
                                                   unsigned short* __restrict__ Btb) {
    __shared__ float tile[32][33];
    int e0 = blockIdx.x * 32;   // column in cat space
    int k0 = blockIdx.y * 32;   // row of W
    const float* W; int eo;
    if (e0 >= 2 * D_IN)      { W = Wc; eo = e0 - 2 * D_IN; }
    else if (e0 >= D_IN)     { W = Wb; eo = e0 - D_IN; }
    else                     { W = Wdt; eo = e0; }
    int tx = threadIdx.x, ty = threadIdx.y;
#pragma unroll
    for (int i = ty; i < 32; i += 8)
        tile[i][tx] = W[(size_t)(k0 + i) * D_IN + eo + tx];
    __syncthreads();
#pragma unroll
    for (int i = ty; i < 32; i += 8)
        Btb[(size_t)(e0 + i) * D_IN + k0 + tx] = f2bf(tile[tx][i]);
}

// ---------------- fused projection GEMM: 128x128, BK=64, m97 family ----------------
// r11 (633us proven) with barriers halved: 32 K-iterations instead of 64.
// Row = 64 elems = 8 slots of 16B; swizzle slot' = slot ^ (row&7) (both-sides:
// pre-swizzled global source + swizzled ds_read; 2 rows/slot-group = free 2-way).
__global__ __launch_bounds__(256) void k_gemm(const unsigned short* __restrict__ Au,
                                              const unsigned short* __restrict__ Btb,
                                              const float* __restrict__ bdt,
                                              const float* __restrict__ bbv,
                                              const float* __restrict__ bcv,
                                              unsigned short* __restrict__ dtp,
                                              unsigned short* __restrict__ btp,
                                              unsigned short* __restrict__ ctp) {
    __shared__ unsigned short As[128 * BK];   // 16 KiB
    __shared__ unsigned short Bs[128 * BK];   // 16 KiB

    int tid = threadIdx.x;
    int lane = tid & 63, wave = tid >> 6;
    int wr = wave >> 1, wc = wave & 1;        // 2x2 waves of 64x64
    int l15 = lane & 15, lhi = lane >> 4;

    int flat = blockIdx.x;                    // natural order (r11: best FETCH)
    int bm = flat / 48, bn = flat % 48;

    const unsigned short* Ag = Au + (size_t)(bm * 128) * D_IN;
    const unsigned short* Bg = Btb + (size_t)(bn * 128) * D_IN;

    f32x4 acc[4][4] = {};

    // staging: 4 x 16B per thread per matrix (1024 slots of 16B per matrix)
    int srow[4]; size_t gsw[4];
#pragma unroll
    for (int q = 0; q < 4; ++q) {
        int s = q * 256 + tid;
        int row = s >> 3, slot = s & 7;
        srow[q] = s;
        gsw[q] = (size_t)row * D_IN + ((slot ^ (row & 7)) * 8);
    }

    // ds_read: fragment row = (wr|wc)*64 + i*16 + l15 -> row&7 = l15&7
    // slot(ks) = ks*4 + lhi; swizzled slot = (ks*4+lhi) ^ (l15&7)
    const int swz0 = ((0 + lhi) ^ (l15 & 7)) * 8;   // ks=0
    const int swz1 = ((4 + lhi) ^ (l15 & 7)) * 8;   // ks=1
    const int arow = (wr * 64 + l15) * BK;
    const int brow = (wc * 64 + l15) * BK;

    for (int kt = 0; kt < D_IN; kt += BK) {
        __syncthreads();
#pragma unroll
        for (int q = 0; q < 4; ++q)
            gload_lds16(Ag + kt + gsw[q], &As[srow[q] * 8]);
#pragma unroll
        for (int q = 0; q < 4; ++q)
            gload_lds16(Bg + kt + gsw[q], &Bs[srow[q] * 8]);
        __syncthreads();
#pragma unroll
        for (int ks = 0; ks < 2; ++ks) {
            int swz = ks ? swz1 : swz0;
            bf16x8 af[4], bfr[4];
#pragma unroll
            for (int i = 0; i < 4; ++i)
                af[i] = *(const bf16x8*)&As[arow + i * 16 * BK + swz];
#pragma unroll
            for (int j = 0; j < 4; ++j)
                bfr[j] = *(const bf16x8*)&Bs[brow + j * 16 * BK + swz];
#pragma unroll
            for (int i = 0; i < 4; ++i)
#pragma unroll
                for (int j = 0; j < 4; ++j)
                    acc[i][j] = __builtin_amdgcn_mfma_f32_16x16x32_bf16(af[i], bfr[j], acc[i][j], 0, 0, 0);
        }
    }

    // ---- epilogue: region uniform per block (bn>>4), bf16 out ----
    int gm0 = bm * 128 + wr * 64 + lhi * 4;
    int col0 = (bn & 15) * 128 + wc * 64 + l15;   // column within 2048-wide region
    int region = bn >> 4;                         // 0: dt, 1: b, 2: c
    unsigned short* outp = (region == 0) ? dtp : (region == 1) ? btp : ctp;
    const float* biasp = (region == 0) ? bdt : (region == 1) ? bbv : bcv;
#pragma unroll
    for (int j = 0; j < 4; ++j) {
        int col = col0 + j * 16;
        float bias = biasp[col];
#pragma unroll
        for (int i = 0; i < 4; ++i)
#pragma unroll
            for (int r = 0; r < 4; ++r) {
                float v = acc[i][j][r] + bias;
                if (region == 0) v = softplus_f(v) + 1e-4f;
                outp[(size_t)(gm0 + i * 16 + r) * D_IN + col] = f2bf(v);
            }
    }
}

// ================= chunked scan, lane = d =================
__device__ __forceinline__ void loadA4(const unsigned short* __restrict__ ub,
                                       const unsigned short* __restrict__ dtp,
                                       const unsigned short* __restrict__ btp,
                                       size_t base, int l0,
                                       float (&T)[4], float (&U)[4], float (&Bv)[4]) {
#pragma unroll
    for (int i = 0; i < 4; ++i) {
        size_t off = base + (size_t)(l0 + i) * D_IN;
        T[i] = bf2f(dtp[off]);
        U[i] = bf2f(ub[off]);
        Bv[i] = bf2f(btp[off]);
    }
}

__device__ __forceinline__ void compA4(float (&x)[16], float& sdt,
                                       const float (&A2)[16], const float (&Bb)[16],
                                       const float (&T)[4], const float (&U)[4],
                                       const float (&Bv)[4]) {
#pragma unroll
    for (int i = 0; i < 4; ++i) {
        float dtv = T[i];
        float s = dtv * Bv[i] * U[i];
        sdt += dtv;
#pragma unroll
        for (int n = 0; n < 16; ++n)
            x[n] = fmaf(exp2f(A2[n] * dtv), x[n], s * Bb[n]);
    }
}

__global__ __launch_bounds__(256) void k_scanA(const unsigned short* __restrict__ ub,
                                               const unsigned short* __restrict__ dtp,
                                               const unsigned short* __restrict__ btp,
                                               const float* __restrict__ a_raw,
                                               const float* __restrict__ Bbp,
                                               float* __restrict__ localx,
                                               float* __restrict__ sumdt) {
    int tid = threadIdx.x;
    int d = blockIdx.x * 256 + tid;
    int c = blockIdx.y, b = blockIdx.z;
    const float L2E = 1.4426950408889634f;

    float A2[16], Bb[16];
#pragma unroll
    for (int n = 0; n < 16; n += 4) {
        f32x4 a = *(const f32x4*)(a_raw + d * STATE_N + n);
        f32x4 bv = *(const f32x4*)(Bbp + d * STATE_N + n);
#pragma unroll
        for (int j = 0; j < 4; ++j) {
            A2[n + j] = -softplus_f(a[j]) * L2E;
            Bb[n + j] = bv[j];
        }
    }

    size_t base = ((size_t)b * SEQ_L + (size_t)c * LC) * D_IN + d;
    float x[16];
#pragma unroll
    for (int n = 0; n < 16; ++n) x[n] = 0.f;
    float sdt = 0.f;

    float tA[4], uA[4], bA[4], tB[4], uB[4], bB[4];
    loadA4(ub, dtp, btp, base, 0, tA, uA, bA);
    for (int l0 = 0; l0 < LC; l0 += 8) {
        loadA4(ub, dtp, btp, base, l0 + 4, tB, uB, bB);
        compA4(x, sdt, A2, Bb, tA, uA, bA);
        if (l0 + 8 < LC)
            loadA4(ub, dtp, btp, base, l0 + 8, tA, uA, bA);
        compA4(x, sdt, A2, Bb, tB, uB, bB);
    }

    size_t sb = (size_t)c * BDN + ((size_t)b * D_IN + d) * STATE_N;
#pragma unroll
    for (int n = 0; n < 16; n += 4) {
        f32x4 v; v[0] = x[n]; v[1] = x[n + 1]; v[2] = x[n + 2]; v[3] = x[n + 3];
        *(f32x4*)(localx + sb + n) = v;
    }
    sumdt[(size_t)c * BD + (size_t)b * D_IN + d] = sdt;
}

// Pass B: combine chunk summaries -> per-chunk start states + carry.
__global__ __launch_bounds__(256) void k_scanB(const float* __restrict__ localx,
                                               const float* __restrict__ sumdt,
                                               const float* __restrict__ a_raw,
                                               float* __restrict__ x0,
                                               float* __restrict__ carry) {
    int gid = blockIdx.x * 256 + threadIdx.x;   // = (b*D_IN + d)*16 + n
    int n = gid & 15;
    int d = (gid >> 4) & (D_IN - 1);
    int bd = gid >> 4;
    float A2 = -softplus_f(a_raw[d * STATE_N + n]) * 1.4426950408889634f;
    float x = 0.f;
    for (int c = 0; c < NCHUNK; ++c) {
        x0[(size_t)c * BDN + gid] = x;
        float sdt = sumdt[(size_t)c * BD + bd];
        x = fmaf(exp2f(A2 * sdt), x, localx[(size_t)c * BDN + gid]);
    }
    carry[gid] = x;
}

// Pass C: re-scan each chunk from its true start state, emit y.
__device__ __forceinline__ void loadC4(const unsigned short* __restrict__ ub,
                                       const unsigned short* __restrict__ dtp,
                                       const unsigned short* __restrict__ btp,
                                       const unsigned short* __restrict__ ctp,
                                       size_t base, int l0,
                                       float (&T)[4], float (&U)[4],
                                       float (&Bv)[4], float (&Cv)[4]) {
#pragma unroll
    for (int i = 0; i < 4; ++i) {
        size_t off = base + (size_t)(l0 + i) * D_IN;
        T[i] = bf2f(dtp[off]);
        U[i] = bf2f(ub[off]);
        Bv[i] = bf2f(btp[off]);
        Cv[i] = bf2f(ctp[off]);
    }
}

__device__ __forceinline__ void compC4(float (&x)[16],
                                       const float (&A2)[16], const float (&Bb)[16],
                                       const float (&Cb)[16], float Dd,
                                       float* __restrict__ y, size_t base, int l0,
                                       const float (&T)[4], const float (&U)[4],
                                       const float (&Bv)[4], const float (&Cv)[4]) {
#pragma unroll
    for (int i = 0; i < 4; ++i) {
        float dtv = T[i], uv = U[i];
        float s = dtv * Bv[i] * uv;
        float y0 = 0.f, y1 = 0.f, y2 = 0.f, y3 = 0.f;
#pragma unroll
        for (int n = 0; n < 16; n += 4) {
            x[n]     = fmaf(exp2f(A2[n] * dtv),     x[n],     s * Bb[n]);
            y0 = fmaf(Cb[n], x[n], y0);
            x[n + 1] = fmaf(exp2f(A2[n + 1] * dtv), x[n + 1], s * Bb[n + 1]);
            y1 = fmaf(Cb[n + 1], x[n + 1], y1);
            x[n + 2] = fmaf(exp2f(A2[n + 2] * dtv), x[n + 2], s * Bb[n + 2]);
            y2 = fmaf(Cb[n + 2], x[n + 2], y2);
            x[n + 3] = fmaf(exp2f(A2[n + 3] * dtv), x[n + 3], s * Bb[n + 3]);
            y3 = fmaf(Cb[n + 3], x[n + 3], y3);
        }
        y[base + (size_t)(l0 + i) * D_IN] = fmaf(Dd, uv, Cv[i] * ((y0 + y1) + (y2 + y3)));
    }
}

__global__ __launch_bounds__(256) void k_scanC(const unsigned short* __restrict__ ub,
                                               const unsigned short* __restrict__ dtp,
                                               const unsigned short* __restrict__ btp,
                                               const unsigned short* __restrict__ ctp,
                                               const float* __restrict__ a_raw,
                                               const float* __restrict__ Bbp,
                                               const float* __restrict__ Cbp,
                                               const float* __restrict__ Dv,
                                               const float* __restrict__ x0,
                                               float* __restrict__ y) {
    int tid = threadIdx.x;
    int d = blockIdx.x * 256 + tid;
    int c = blockIdx.y, b = blockIdx.z;
    const float L2E = 1.4426950408889634f;

    float A2[16], Bb[16], Cb[16];
#pragma unroll
    for (int n = 0; n < 16; n += 4) {
        f32x4 a = *(const f32x4*)(a_raw + d * STATE_N + n);
        f32x4 bv = *(const f32x4*)(Bbp + d * STATE_N + n);
        f32x4 cv = *(const f32x4*)(Cbp + d * STATE_N + n);
#pragma unroll
        for (int j = 0; j < 4; ++j) {
            A2[n + j] = -softplus_f(a[j]) * L2E;
            Bb[n + j] = bv[j];
            Cb[n + j] = cv[j];
        }
    }
    float Dd = Dv[d];

    float x[16];
    size_t xb = (size_t)c * BDN + ((size_t)b * D_IN + d) * STATE_N;
#pragma unroll
    for (int n = 0; n < 16; n += 4) {
        f32x4 v = *(const f32x4*)(x0 + xb + n);
        x[n] = v[0]; x[n + 1] = v[1]; x[n + 2] = v[2]; x[n + 3] = v[3];
    }

    size_t base = ((size_t)b * SEQ_L + (size_t)c * LC) * D_IN + d;
    float tA[4], uA[4], bA[4], cA[4], tB[4], uB[4], bB[4], cB[4];
    loadC4(ub, dtp, btp, ctp, base, 0, tA, uA, bA, cA);
    for (int l0 = 0; l0 < LC; l0 += 8) {
        loadC4(ub, dtp, btp, ctp, base, l0 + 4, tB, uB, bB, cB);
        compC4(x, A2, Bb, Cb, Dd, y, base, l0, tA, uA, bA, cA);
        if (l0 + 8 < LC)
            loadC4(ub, dtp, btp, ctp, base, l0 + 8, tA, uA, bA, cA);
        compC4(x, A2, Bb, Cb, Dd, y, base, l0 + 4, tB, uB, bB, cB);
    }
}

// ---------------- launch ----------------
extern "C" void kernel_launch(void* const* d_in, const int* in_sizes, int n_in,
                              void* d_out, int out_size, void* d_ws, size_t ws_size,
                              hipStream_t stream) {
    const float* u     = (const float*)d_in[0];
    const float* Wdt   = (const float*)d_in[1];
    const float* bdt   = (const float*)d_in[2];
    const float* Wb    = (const float*)d_in[3];
    const float* bb    = (const float*)d_in[4];
    const float* Wc    = (const float*)d_in[5];
    const float* bc    = (const float*)d_in[6];
    const float* a_raw = (const float*)d_in[7];
    const float* Bbp   = (const float*)d_in[8];
    const float* Cbp   = (const float*)d_in[9];
    const float* Dv    = (const float*)d_in[10];

    float* out = (float*)d_out;
    float* carry = out;                                      // (B, d, N)
    float* y = out + (size_t)BATCH * D_IN * STATE_N;         // (B, L, d)

    const size_t Mel = (size_t)M_TOT * D_IN;                 // 33.5M elements
    char* ws = (char*)d_ws;
    unsigned short* ub  = (unsigned short*)ws;                          // Mel*2
    unsigned short* Btb = (unsigned short*)(ws + Mel * 2);              // NCAT*D_IN*2
    char* p = ws + Mel * 2 + (size_t)NCAT * D_IN * 2;
    unsigned short* dtp = (unsigned short*)p;                           // Mel*2
    unsigned short* btp = (unsigned short*)(p + Mel * 2);               // Mel*2
    unsigned short* ctp = (unsigned short*)(p + Mel * 4);               // Mel*2
    char* q = p + Mel * 6;
    float* localx = (float*)q;                                          // NCHUNK*BDN*4
    float* x0v    = (float*)(q + (size_t)NCHUNK * BDN * 4);             // NCHUNK*BDN*4
    float* sumdt  = (float*)(q + (size_t)NCHUNK * BDN * 8);             // NCHUNK*BD*4

    k_cvt_u<<<dim3((M_TOT * D_IN) / (256 * 8)), dim3(256), 0, stream>>>(u, ub);
    k_transpose<<<dim3(NCAT / 32, D_IN / 32), dim3(32, 8), 0, stream>>>(Wdt, Wb, Wc, Btb);
    k_gemm<<<dim3((M_TOT / 128) * (NCAT / 128)), dim3(256), 0, stream>>>(ub, Btb, bdt, bb, bc,
                                                                         dtp, btp, ctp);
    k_scanA<<<dim3(D_IN / 256, NCHUNK, BATCH), dim3(256), 0, stream>>>(ub, dtp, btp, a_raw,
                                                                       Bbp, localx, sumdt);
    k_scanB<<<dim3(BDN / 256), dim3(256), 0, stream>>>(localx, sumdt, a_raw, x0v, carry);
    k_scanC<<<dim3(D_IN / 256, NCHUNK, BATCH), dim3(256), 0, stream>>>(ub, dtp, btp, ctp,
                                                                       a_raw, Bbp, Cbp, Dv,
                                                                       x0v, y);
}

// Round 13
// 1139.317 us; speedup vs baseline: 1.0334x; 1.0334x over previous
//
#include <hip/hip_runtime.h>
#include <cstdint>
#include <cstddef>

// ---- problem constants ----
#define D_IN   2048
#define STATE_N 16
#define SEQ_L  4096
#define BATCH  4
#define M_TOT  (BATCH * SEQ_L)   // 16384
#define NCAT   (3 * D_IN)        // 6144
#define LC     128               // scan chunk length
#define NCHUNK (SEQ_L / LC)      // 32
#define BDN    (BATCH * D_IN * STATE_N)  // 131072
#define BD     (BATCH * D_IN)            // 8192

// GEMM tile params: 128x128 tile (m97 structure), BK=32, single-buffer LDS,
// 256 thr / 4 waves -> ~3 blocks/CU co-resident (m114 cross-block overlap).
#define BK     32

typedef __bf16 bf16x8 __attribute__((ext_vector_type(8)));
typedef float  f32x4  __attribute__((ext_vector_type(4)));
typedef unsigned int u32x4 __attribute__((ext_vector_type(4)));

__device__ __forceinline__ float softplus_f(float x) {
    return log1pf(expf(-fabsf(x))) + fmaxf(x, 0.f);
}
__device__ __forceinline__ unsigned short f2bf(float f) {  // RNE f32->bf16
    unsigned u = __float_as_uint(f);
    u += 0x7FFFu + ((u >> 16) & 1u);
    return (unsigned short)(u >> 16);
}
__device__ __forceinline__ float bf2f(unsigned short h) {
    return __uint_as_float(((unsigned)h) << 16);
}

// async global->LDS, 16B per lane (wave-uniform LDS base + lane*16 pattern)
__device__ __forceinline__ void gload_lds16(const unsigned short* g, unsigned short* l) {
    __builtin_amdgcn_global_load_lds(
        (const __attribute__((address_space(1))) unsigned int*)(const void*)g,
        (__attribute__((address_space(3))) unsigned int*)(void*)l,
        16, 0, 0);
}

// ---------------- u -> bf16 ----------------
__global__ __launch_bounds__(256) void k_cvt_u(const float* __restrict__ u,
                                               unsigned short* __restrict__ ub) {
    size_t i = ((size_t)blockIdx.x * 256 + threadIdx.x) * 8;
    f32x4 a = *(const f32x4*)(u + i);
    f32x4 b = *(const f32x4*)(u + i + 4);
    u32x4 o;
    o[0] = (unsigned)f2bf(a[0]) | ((unsigned)f2bf(a[1]) << 16);
    o[1] = (unsigned)f2bf(a[2]) | ((unsigned)f2bf(a[3]) << 16);
    o[2] = (unsigned)f2bf(b[0]) | ((unsigned)f2bf(b[1]) << 16);
    o[3] = (unsigned)f2bf(b[2]) | ((unsigned)f2bf(b[3]) << 16);
    *(u32x4*)(ub + i) = o;
}

// ---------------- W(cat) -> Wt bf16 (NCAT x K) ----------------
__global__ __launch_bounds__(256) void k_transpose(const float* __restrict__ Wdt,
                                                   const float* __restrict__ Wb,
                                                   const float* __restrict__ Wc,
                                                   unsigned short* __restrict__ Btb) {
    __shared__ float tile[32][33];
    int e0 = blockIdx.x * 32;   // column in cat space
    int k0 = blockIdx.y * 32;   // row of W
    const float* W; int eo;
    if (e0 >= 2 * D_IN)      { W = Wc; eo = e0 - 2 * D_IN; }
    else if (e0 >= D_IN)     { W = Wb; eo = e0 - D_IN; }
    else                     { W = Wdt; eo = e0; }
    int tx = threadIdx.x, ty = threadIdx.y;
#pragma unroll
    for (int i = ty; i < 32; i += 8)
        tile[i][tx] = W[(size_t)(k0 + i) * D_IN + eo + tx];
    __syncthreads();
#pragma unroll
    for (int i = ty; i < 32; i += 8)
        Btb[(size_t)(e0 + i) * D_IN + k0 + tx] = f2bf(tile[tx][i]);
}

// ---------------- fused projection GEMM: r11-EXACT (633us proven) ----------------
__global__ __launch_bounds__(256) void k_gemm(const unsigned short* __restrict__ Au,
                                              const unsigned short* __restrict__ Btb,
                                              const float* __restrict__ bdt,
                                              const float* __restrict__ bbv,
                                              const float* __restrict__ bcv,
                                              unsigned short* __restrict__ dtp,
                                              unsigned short* __restrict__ btp,
                                              unsigned short* __restrict__ ctp) {
    __shared__ unsigned short As[128 * BK];   // 8 KiB
    __shared__ unsigned short Bs[128 * BK];   // 8 KiB

    int tid = threadIdx.x;
    int lane = tid & 63, wave = tid >> 6;
    int wr = wave >> 1, wc = wave & 1;        // 2x2 waves of 64x64
    int l15 = lane & 15, lhi = lane >> 4;

    int flat = blockIdx.x;                    // natural order: bn-fast
    int bm = flat / 48, bn = flat % 48;

    const unsigned short* Ag = Au + (size_t)(bm * 128) * D_IN;
    const unsigned short* Bg = Btb + (size_t)(bn * 128) * D_IN;

    f32x4 acc[4][4] = {};

    // staging: 2 x 16B per thread per matrix; slot XOR-swizzled via global src
    const int s0 = tid, s1 = 256 + tid;
    const int r0 = s0 >> 2, r1 = s1 >> 2;
    const size_t ga0 = (size_t)r0 * D_IN + (((s0 & 3) ^ ((r0 >> 1) & 3)) * 8);
    const size_t ga1 = (size_t)r1 * D_IN + (((s1 & 3) ^ ((r1 >> 1) & 3)) * 8);

    // ds_read: fragment row = base + l15 -> slot' = lhi ^ ((l15>>1)&3) (lane-const)
    const int swzr = (lhi ^ ((l15 >> 1) & 3)) * 8;
    const int aoff = (wr * 64 + l15) * BK + swzr;
    const int boff = (wc * 64 + l15) * BK + swzr;

    for (int kt = 0; kt < D_IN; kt += BK) {
        __syncthreads();
        gload_lds16(Ag + kt + ga0, &As[s0 * 8]);
        gload_lds16(Ag + kt + ga1, &As[s1 * 8]);
        gload_lds16(Bg + kt + ga0, &Bs[s0 * 8]);
        gload_lds16(Bg + kt + ga1, &Bs[s1 * 8]);
        __syncthreads();
        bf16x8 af[4], bfr[4];
#pragma unroll
        for (int i = 0; i < 4; ++i)
            af[i] = *(const bf16x8*)&As[aoff + i * 16 * BK];
#pragma unroll
        for (int j = 0; j < 4; ++j)
            bfr[j] = *(const bf16x8*)&Bs[boff + j * 16 * BK];
#pragma unroll
        for (int i = 0; i < 4; ++i)
#pragma unroll
            for (int j = 0; j < 4; ++j)
                acc[i][j] = __builtin_amdgcn_mfma_f32_16x16x32_bf16(af[i], bfr[j], acc[i][j], 0, 0, 0);
    }

    // ---- epilogue: region uniform per block (bn>>4), bf16 out ----
    int gm0 = bm * 128 + wr * 64 + lhi * 4;
    int col0 = (bn & 15) * 128 + wc * 64 + l15;   // column within 2048-wide region
    int region = bn >> 4;                         // 0: dt, 1: b, 2: c
    unsigned short* outp = (region == 0) ? dtp : (region == 1) ? btp : ctp;
    const float* biasp = (region == 0) ? bdt : (region == 1) ? bbv : bcv;
#pragma unroll
    for (int j = 0; j < 4; ++j) {
        int col = col0 + j * 16;
        float bias = biasp[col];
#pragma unroll
        for (int i = 0; i < 4; ++i)
#pragma unroll
            for (int r = 0; r < 4; ++r) {
                float v = acc[i][j][r] + bias;
                if (region == 0) v = softplus_f(v) + 1e-4f;
                outp[(size_t)(gm0 + i * 16 + r) * D_IN + col] = f2bf(v);
            }
    }
}

// ================= chunked scan, lane = d, 8-step double-buffered =================
__device__ __forceinline__ void loadA8(const unsigned short* __restrict__ ub,
                                       const unsigned short* __restrict__ dtp,
                                       const unsigned short* __restrict__ btp,
                                       size_t base, int l0,
                                       float (&T)[8], float (&U)[8], float (&Bv)[8]) {
#pragma unroll
    for (int i = 0; i < 8; ++i) {
        size_t off = base + (size_t)(l0 + i) * D_IN;
        T[i] = bf2f(dtp[off]);
        U[i] = bf2f(ub[off]);
        Bv[i] = bf2f(btp[off]);
    }
}

__device__ __forceinline__ void compA8(float (&x)[16], float& sdt,
                                       const float (&A2)[16], const float (&Bb)[16],
                                       const float (&T)[8], const float (&U)[8],
                                       const float (&Bv)[8]) {
#pragma unroll
    for (int i = 0; i < 8; ++i) {
        float dtv = T[i];
        float s = dtv * Bv[i] * U[i];
        sdt += dtv;
#pragma unroll
        for (int n = 0; n < 16; ++n)
            x[n] = fmaf(exp2f(A2[n] * dtv), x[n], s * Bb[n]);
    }
}

__global__ __launch_bounds__(256) void k_scanA(const unsigned short* __restrict__ ub,
                                               const unsigned short* __restrict__ dtp,
                                               const unsigned short* __restrict__ btp,
                                               const float* __restrict__ a_raw,
                                               const float* __restrict__ Bbp,
                                               float* __restrict__ localx,
                                               float* __restrict__ sumdt) {
    int tid = threadIdx.x;
    int d = blockIdx.x * 256 + tid;
    int c = blockIdx.y, b = blockIdx.z;
    const float L2E = 1.4426950408889634f;

    float A2[16], Bb[16];
#pragma unroll
    for (int n = 0; n < 16; n += 4) {
        f32x4 a = *(const f32x4*)(a_raw + d * STATE_N + n);
        f32x4 bv = *(const f32x4*)(Bbp + d * STATE_N + n);
#pragma unroll
        for (int j = 0; j < 4; ++j) {
            A2[n + j] = -softplus_f(a[j]) * L2E;
            Bb[n + j] = bv[j];
        }
    }

    size_t base = ((size_t)b * SEQ_L + (size_t)c * LC) * D_IN + d;
    float x[16];
#pragma unroll
    for (int n = 0; n < 16; ++n) x[n] = 0.f;
    float sdt = 0.f;

    float tA[8], uA[8], bA[8], tB[8], uB[8], bB[8];
    loadA8(ub, dtp, btp, base, 0, tA, uA, bA);
    for (int l0 = 0; l0 < LC; l0 += 16) {
        loadA8(ub, dtp, btp, base, l0 + 8, tB, uB, bB);
        compA8(x, sdt, A2, Bb, tA, uA, bA);
        if (l0 + 16 < LC)
            loadA8(ub, dtp, btp, base, l0 + 16, tA, uA, bA);
        compA8(x, sdt, A2, Bb, tB, uB, bB);
    }

    size_t sb = (size_t)c * BDN + ((size_t)b * D_IN + d) * STATE_N;
#pragma unroll
    for (int n = 0; n < 16; n += 4) {
        f32x4 v; v[0] = x[n]; v[1] = x[n + 1]; v[2] = x[n + 2]; v[3] = x[n + 3];
        *(f32x4*)(localx + sb + n) = v;
    }
    sumdt[(size_t)c * BD + (size_t)b * D_IN + d] = sdt;
}

// Pass B: combine chunk summaries -> per-chunk start states + carry.
__global__ __launch_bounds__(256) void k_scanB(const float* __restrict__ localx,
                                               const float* __restrict__ sumdt,
                                               const float* __restrict__ a_raw,
                                               float* __restrict__ x0,
                                               float* __restrict__ carry) {
    int gid = blockIdx.x * 256 + threadIdx.x;   // = (b*D_IN + d)*16 + n
    int n = gid & 15;
    int d = (gid >> 4) & (D_IN - 1);
    int bd = gid >> 4;
    float A2 = -softplus_f(a_raw[d * STATE_N + n]) * 1.4426950408889634f;
    float x = 0.f;
    for (int c = 0; c < NCHUNK; ++c) {
        x0[(size_t)c * BDN + gid] = x;
        float sdt = sumdt[(size_t)c * BD + bd];
        x = fmaf(exp2f(A2 * sdt), x, localx[(size_t)c * BDN + gid]);
    }
    carry[gid] = x;
}

// Pass C: re-scan each chunk from its true start state, emit y.
__device__ __forceinline__ void loadC8(const unsigned short* __restrict__ ub,
                                       const unsigned short* __restrict__ dtp,
                                       const unsigned short* __restrict__ btp,
                                       const unsigned short* __restrict__ ctp,
                                       size_t base, int l0,
                                       float (&T)[8], float (&U)[8],
                                       float (&Bv)[8], float (&Cv)[8]) {
#pragma unroll
    for (int i = 0; i < 8; ++i) {
        size_t off = base + (size_t)(l0 + i) * D_IN;
        T[i] = bf2f(dtp[off]);
        U[i] = bf2f(ub[off]);
        Bv[i] = bf2f(btp[off]);
        Cv[i] = bf2f(ctp[off]);
    }
}

__device__ __forceinline__ void compC8(float (&x)[16],
                                       const float (&A2)[16], const float (&Bb)[16],
                                       const float (&Cb)[16], float Dd,
                                       float* __restrict__ y, size_t base, int l0,
                                       const float (&T)[8], const float (&U)[8],
                                       const float (&Bv)[8], const float (&Cv)[8]) {
#pragma unroll
    for (int i = 0; i < 8; ++i) {
        float dtv = T[i], uv = U[i];
        float s = dtv * Bv[i] * uv;
        float y0 = 0.f, y1 = 0.f, y2 = 0.f, y3 = 0.f;
#pragma unroll
        for (int n = 0; n < 16; n += 4) {
            x[n]     = fmaf(exp2f(A2[n] * dtv),     x[n],     s * Bb[n]);
            y0 = fmaf(Cb[n], x[n], y0);
            x[n + 1] = fmaf(exp2f(A2[n + 1] * dtv), x[n + 1], s * Bb[n + 1]);
            y1 = fmaf(Cb[n + 1], x[n + 1], y1);
            x[n + 2] = fmaf(exp2f(A2[n + 2] * dtv), x[n + 2], s * Bb[n + 2]);
            y2 = fmaf(Cb[n + 2], x[n + 2], y2);
            x[n + 3] = fmaf(exp2f(A2[n + 3] * dtv), x[n + 3], s * Bb[n + 3]);
            y3 = fmaf(Cb[n + 3], x[n + 3], y3);
        }
        y[base + (size_t)(l0 + i) * D_IN] = fmaf(Dd, uv, Cv[i] * ((y0 + y1) + (y2 + y3)));
    }
}

__global__ __launch_bounds__(256) void k_scanC(const unsigned short* __restrict__ ub,
                                               const unsigned short* __restrict__ dtp,
                                               const unsigned short* __restrict__ btp,
                                               const unsigned short* __restrict__ ctp,
                                               const float* __restrict__ a_raw,
                                               const float* __restrict__ Bbp,
                                               const float* __restrict__ Cbp,
                                               const float* __restrict__ Dv,
                                               const float* __restrict__ x0,
                                               float* __restrict__ y) {
    int tid = threadIdx.x;
    int d = blockIdx.x * 256 + tid;
    int c = blockIdx.y, b = blockIdx.z;
    const float L2E = 1.4426950408889634f;

    float A2[16], Bb[16], Cb[16];
#pragma unroll
    for (int n = 0; n < 16; n += 4) {
        f32x4 a = *(const f32x4*)(a_raw + d * STATE_N + n);
        f32x4 bv = *(const f32x4*)(Bbp + d * STATE_N + n);
        f32x4 cv = *(const f32x4*)(Cbp + d * STATE_N + n);
#pragma unroll
        for (int j = 0; j < 4; ++j) {
            A2[n + j] = -softplus_f(a[j]) * L2E;
            Bb[n + j] = bv[j];
            Cb[n + j] = cv[j];
        }
    }
    float Dd = Dv[d];

    float x[16];
    size_t xb = (size_t)c * BDN + ((size_t)b * D_IN + d) * STATE_N;
#pragma unroll
    for (int n = 0; n < 16; n += 4) {
        f32x4 v = *(const f32x4*)(x0 + xb + n);
        x[n] = v[0]; x[n + 1] = v[1]; x[n + 2] = v[2]; x[n + 3] = v[3];
    }

    size_t base = ((size_t)b * SEQ_L + (size_t)c * LC) * D_IN + d;
    float tA[8], uA[8], bA[8], cA[8], tB[8], uB[8], bB[8], cB[8];
    loadC8(ub, dtp, btp, ctp, base, 0, tA, uA, bA, cA);
    for (int l0 = 0; l0 < LC; l0 += 16) {
        loadC8(ub, dtp, btp, ctp, base, l0 + 8, tB, uB, bB, cB);
        compC8(x, A2, Bb, Cb, Dd, y, base, l0, tA, uA, bA, cA);
        if (l0 + 16 < LC)
            loadC8(ub, dtp, btp, ctp, base, l0 + 16, tA, uA, bA, cA);
        compC8(x, A2, Bb, Cb, Dd, y, base, l0 + 8, tB, uB, bB, cB);
    }
}

// ---------------- launch ----------------
extern "C" void kernel_launch(void* const* d_in, const int* in_sizes, int n_in,
                              void* d_out, int out_size, void* d_ws, size_t ws_size,
                              hipStream_t stream) {
    const float* u     = (const float*)d_in[0];
    const float* Wdt   = (const float*)d_in[1];
    const float* bdt   = (const float*)d_in[2];
    const float* Wb    = (const float*)d_in[3];
    const float* bb    = (const float*)d_in[4];
    const float* Wc    = (const float*)d_in[5];
    const float* bc    = (const float*)d_in[6];
    const float* a_raw = (const float*)d_in[7];
    const float* Bbp   = (const float*)d_in[8];
    const float* Cbp   = (const float*)d_in[9];
    const float* Dv    = (const float*)d_in[10];

    float* out = (float*)d_out;
    float* carry = out;                                      // (B, d, N)
    float* y = out + (size_t)BATCH * D_IN * STATE_N;         // (B, L, d)

    const size_t Mel = (size_t)M_TOT * D_IN;                 // 33.5M elements
    char* ws = (char*)d_ws;
    unsigned short* ub  = (unsigned short*)ws;                          // Mel*2
    unsigned short* Btb = (unsigned short*)(ws + Mel * 2);              // NCAT*D_IN*2
    char* p = ws + Mel * 2 + (size_t)NCAT * D_IN * 2;
    unsigned short* dtp = (unsigned short*)p;                           // Mel*2
    unsigned short* btp = (unsigned short*)(p + Mel * 2);               // Mel*2
    unsigned short* ctp = (unsigned short*)(p + Mel * 4);               // Mel*2
    char* q = p + Mel * 6;
    float* localx = (float*)q;                                          // NCHUNK*BDN*4
    float* x0v    = (float*)(q + (size_t)NCHUNK * BDN * 4);             // NCHUNK*BDN*4
    float* sumdt  = (float*)(q + (size_t)NCHUNK * BDN * 8);             // NCHUNK*BD*4

    k_cvt_u<<<dim3((M_TOT * D_IN) / (256 * 8)), dim3(256), 0, stream>>>(u, ub);
    k_transpose<<<dim3(NCAT / 32, D_IN / 32), dim3(32, 8), 0, stream>>>(Wdt, Wb, Wc, Btb);
    k_gemm<<<dim3((M_TOT / 128) * (NCAT / 128)), dim3(256), 0, stream>>>(ub, Btb, bdt, bb, bc,
                                                                         dtp, btp, ctp);
    k_scanA<<<dim3(D_IN / 256, NCHUNK, BATCH), dim3(256), 0, stream>>>(ub, dtp, btp, a_raw,
                                                                       Bbp, localx, sumdt);
    k_scanB<<<dim3(BDN / 256), dim3(256), 0, stream>>>(localx, sumdt, a_raw, x0v, carry);
    k_scanC<<<dim3(D_IN / 256, NCHUNK, BATCH), dim3(256), 0, stream>>>(ub, dtp, btp, ctp,
                                                                       a_raw, Bbp, Cbp, Dv,
                                                                       x0v, y);
}

// Round 14
// 1047.132 us; speedup vs baseline: 1.1243x; 1.0880x over previous
//
#include <hip/hip_runtime.h>
#include <cstdint>
#include <cstddef>

// ---- problem constants ----
#define D_IN   2048
#define STATE_N 16
#define SEQ_L  4096
#define BATCH  4
#define M_TOT  (BATCH * SEQ_L)   // 16384
#define NCAT   (3 * D_IN)        // 6144
#define LC     64                // scan chunk length (r14: 128->64 for 2x scan TLP)
#define NCHUNK (SEQ_L / LC)      // 64
#define BDN    (BATCH * D_IN * STATE_N)  // 131072
#define BD     (BATCH * D_IN)            // 8192

// GEMM tile params: 128x128 tile (m97 structure), BK=32, single-buffer LDS,
// 256 thr / 4 waves -> ~3 blocks/CU co-resident (m114 cross-block overlap).
#define BK     32

typedef __bf16 bf16x8 __attribute__((ext_vector_type(8)));
typedef float  f32x4  __attribute__((ext_vector_type(4)));
typedef unsigned int u32x4 __attribute__((ext_vector_type(4)));

__device__ __forceinline__ float softplus_f(float x) {
    return log1pf(expf(-fabsf(x))) + fmaxf(x, 0.f);
}
__device__ __forceinline__ unsigned short f2bf(float f) {  // RNE f32->bf16
    unsigned u = __float_as_uint(f);
    u += 0x7FFFu + ((u >> 16) & 1u);
    return (unsigned short)(u >> 16);
}
__device__ __forceinline__ float bf2f(unsigned short h) {
    return __uint_as_float(((unsigned)h) << 16);
}

// async global->LDS, 16B per lane (wave-uniform LDS base + lane*16 pattern)
__device__ __forceinline__ void gload_lds16(const unsigned short* g, unsigned short* l) {
    __builtin_amdgcn_global_load_lds(
        (const __attribute__((address_space(1))) unsigned int*)(const void*)g,
        (__attribute__((address_space(3))) unsigned int*)(void*)l,
        16, 0, 0);
}

// ---------------- u -> bf16 ----------------
__global__ __launch_bounds__(256) void k_cvt_u(const float* __restrict__ u,
                                               unsigned short* __restrict__ ub) {
    size_t i = ((size_t)blockIdx.x * 256 + threadIdx.x) * 8;
    f32x4 a = *(const f32x4*)(u + i);
    f32x4 b = *(const f32x4*)(u + i + 4);
    u32x4 o;
    o[0] = (unsigned)f2bf(a[0]) | ((unsigned)f2bf(a[1]) << 16);
    o[1] = (unsigned)f2bf(a[2]) | ((unsigned)f2bf(a[3]) << 16);
    o[2] = (unsigned)f2bf(b[0]) | ((unsigned)f2bf(b[1]) << 16);
    o[3] = (unsigned)f2bf(b[2]) | ((unsigned)f2bf(b[3]) << 16);
    *(u32x4*)(ub + i) = o;
}

// ---------------- W(cat) -> Wt bf16 (NCAT x K) ----------------
__global__ __launch_bounds__(256) void k_transpose(const float* __restrict__ Wdt,
                                                   const float* __restrict__ Wb,
                                                   const float* __restrict__ Wc,
                                                   unsigned short* __restrict__ Btb) {
    __shared__ float tile[32][33];
    int e0 = blockIdx.x * 32;   // column in cat space
    int k0 = blockIdx.y * 32;   // row of W
    const float* W; int eo;
    if (e0 >= 2 * D_IN)      { W = Wc; eo = e0 - 2 * D_IN; }
    else if (e0 >= D_IN)     { W = Wb; eo = e0 - D_IN; }
    else                     { W = Wdt; eo = e0; }
    int tx = threadIdx.x, ty = threadIdx.y;
#pragma unroll
    for (int i = ty; i < 32; i += 8)
        tile[i][tx] = W[(size_t)(k0 + i) * D_IN + eo + tx];
    __syncthreads();
#pragma unroll
    for (int i = ty; i < 32; i += 8)
        Btb[(size_t)(e0 + i) * D_IN + k0 + tx] = f2bf(tile[tx][i]);
}

// ---------------- fused projection GEMM: r11-EXACT (633us proven) ----------------
__global__ __launch_bounds__(256) void k_gemm(const unsigned short* __restrict__ Au,
                                              const unsigned short* __restrict__ Btb,
                                              const float* __restrict__ bdt,
                                              const float* __restrict__ bbv,
                                              const float* __restrict__ bcv,
                                              unsigned short* __restrict__ dtp,
                                              unsigned short* __restrict__ btp,
                                              unsigned short* __restrict__ ctp) {
    __shared__ unsigned short As[128 * BK];   // 8 KiB
    __shared__ unsigned short Bs[128 * BK];   // 8 KiB

    int tid = threadIdx.x;
    int lane = tid & 63, wave = tid >> 6;
    int wr = wave >> 1, wc = wave & 1;        // 2x2 waves of 64x64
    int l15 = lane & 15, lhi = lane >> 4;

    int flat = blockIdx.x;                    // natural order: bn-fast
    int bm = flat / 48, bn = flat % 48;

    const unsigned short* Ag = Au + (size_t)(bm * 128) * D_IN;
    const unsigned short* Bg = Btb + (size_t)(bn * 128) * D_IN;

    f32x4 acc[4][4] = {};

    // staging: 2 x 16B per thread per matrix; slot XOR-swizzled via global src
    const int s0 = tid, s1 = 256 + tid;
    const int r0 = s0 >> 2, r1 = s1 >> 2;
    const size_t ga0 = (size_t)r0 * D_IN + (((s0 & 3) ^ ((r0 >> 1) & 3)) * 8);
    const size_t ga1 = (size_t)r1 * D_IN + (((s1 & 3) ^ ((r1 >> 1) & 3)) * 8);

    // ds_read: fragment row = base + l15 -> slot' = lhi ^ ((l15>>1)&3) (lane-const)
    const int swzr = (lhi ^ ((l15 >> 1) & 3)) * 8;
    const int aoff = (wr * 64 + l15) * BK + swzr;
    const int boff = (wc * 64 + l15) * BK + swzr;

    for (int kt = 0; kt < D_IN; kt += BK) {
        __syncthreads();
        gload_lds16(Ag + kt + ga0, &As[s0 * 8]);
        gload_lds16(Ag + kt + ga1, &As[s1 * 8]);
        gload_lds16(Bg + kt + ga0, &Bs[s0 * 8]);
        gload_lds16(Bg + kt + ga1, &Bs[s1 * 8]);
        __syncthreads();
        bf16x8 af[4], bfr[4];
#pragma unroll
        for (int i = 0; i < 4; ++i)
            af[i] = *(const bf16x8*)&As[aoff + i * 16 * BK];
#pragma unroll
        for (int j = 0; j < 4; ++j)
            bfr[j] = *(const bf16x8*)&Bs[boff + j * 16 * BK];
#pragma unroll
        for (int i = 0; i < 4; ++i)
#pragma unroll
            for (int j = 0; j < 4; ++j)
                acc[i][j] = __builtin_amdgcn_mfma_f32_16x16x32_bf16(af[i], bfr[j], acc[i][j], 0, 0, 0);
    }

    // ---- epilogue: region uniform per block (bn>>4), bf16 out ----
    int gm0 = bm * 128 + wr * 64 + lhi * 4;
    int col0 = (bn & 15) * 128 + wc * 64 + l15;   // column within 2048-wide region
    int region = bn >> 4;                         // 0: dt, 1: b, 2: c
    unsigned short* outp = (region == 0) ? dtp : (region == 1) ? btp : ctp;
    const float* biasp = (region == 0) ? bdt : (region == 1) ? bbv : bcv;
#pragma unroll
    for (int j = 0; j < 4; ++j) {
        int col = col0 + j * 16;
        float bias = biasp[col];
#pragma unroll
        for (int i = 0; i < 4; ++i)
#pragma unroll
            for (int r = 0; r < 4; ++r) {
                float v = acc[i][j][r] + bias;
                if (region == 0) v = softplus_f(v) + 1e-4f;
                outp[(size_t)(gm0 + i * 16 + r) * D_IN + col] = f2bf(v);
            }
    }
}

// ================= chunked scan, lane = d, 4-step double-buffered (r11) =================
__device__ __forceinline__ void loadA4(const unsigned short* __restrict__ ub,
                                       const unsigned short* __restrict__ dtp,
                                       const unsigned short* __restrict__ btp,
                                       size_t base, int l0,
                                       float (&T)[4], float (&U)[4], float (&Bv)[4]) {
#pragma unroll
    for (int i = 0; i < 4; ++i) {
        size_t off = base + (size_t)(l0 + i) * D_IN;
        T[i] = bf2f(dtp[off]);
        U[i] = bf2f(ub[off]);
        Bv[i] = bf2f(btp[off]);
    }
}

__device__ __forceinline__ void compA4(float (&x)[16], float& sdt,
                                       const float (&A2)[16], const float (&Bb)[16],
                                       const float (&T)[4], const float (&U)[4],
                                       const float (&Bv)[4]) {
#pragma unroll
    for (int i = 0; i < 4; ++i) {
        float dtv = T[i];
        float s = dtv * Bv[i] * U[i];
        sdt += dtv;
#pragma unroll
        for (int n = 0; n < 16; ++n)
            x[n] = fmaf(exp2f(A2[n] * dtv), x[n], s * Bb[n]);
    }
}

__global__ __launch_bounds__(256) void k_scanA(const unsigned short* __restrict__ ub,
                                               const unsigned short* __restrict__ dtp,
                                               const unsigned short* __restrict__ btp,
                                               const float* __restrict__ a_raw,
                                               const float* __restrict__ Bbp,
                                               float* __restrict__ localx,
                                               float* __restrict__ sumdt) {
    int tid = threadIdx.x;
    int d = blockIdx.x * 256 + tid;
    int c = blockIdx.y, b = blockIdx.z;
    const float L2E = 1.4426950408889634f;

    float A2[16], Bb[16];
#pragma unroll
    for (int n = 0; n < 16; n += 4) {
        f32x4 a = *(const f32x4*)(a_raw + d * STATE_N + n);
        f32x4 bv = *(const f32x4*)(Bbp + d * STATE_N + n);
#pragma unroll
        for (int j = 0; j < 4; ++j) {
            A2[n + j] = -softplus_f(a[j]) * L2E;
            Bb[n + j] = bv[j];
        }
    }

    size_t base = ((size_t)b * SEQ_L + (size_t)c * LC) * D_IN + d;
    float x[16];
#pragma unroll
    for (int n = 0; n < 16; ++n) x[n] = 0.f;
    float sdt = 0.f;

    float tA[4], uA[4], bA[4], tB[4], uB[4], bB[4];
    loadA4(ub, dtp, btp, base, 0, tA, uA, bA);
    for (int l0 = 0; l0 < LC; l0 += 8) {
        loadA4(ub, dtp, btp, base, l0 + 4, tB, uB, bB);
        compA4(x, sdt, A2, Bb, tA, uA, bA);
        if (l0 + 8 < LC)
            loadA4(ub, dtp, btp, base, l0 + 8, tA, uA, bA);
        compA4(x, sdt, A2, Bb, tB, uB, bB);
    }

    size_t sb = (size_t)c * BDN + ((size_t)b * D_IN + d) * STATE_N;
#pragma unroll
    for (int n = 0; n < 16; n += 4) {
        f32x4 v; v[0] = x[n]; v[1] = x[n + 1]; v[2] = x[n + 2]; v[3] = x[n + 3];
        *(f32x4*)(localx + sb + n) = v;
    }
    sumdt[(size_t)c * BD + (size_t)b * D_IN + d] = sdt;
}

// Pass B: combine chunk summaries -> per-chunk start states + carry.
__global__ __launch_bounds__(256) void k_scanB(const float* __restrict__ localx,
                                               const float* __restrict__ sumdt,
                                               const float* __restrict__ a_raw,
                                               float* __restrict__ x0,
                                               float* __restrict__ carry) {
    int gid = blockIdx.x * 256 + threadIdx.x;   // = (b*D_IN + d)*16 + n
    int n = gid & 15;
    int d = (gid >> 4) & (D_IN - 1);
    int bd = gid >> 4;
    float A2 = -softplus_f(a_raw[d * STATE_N + n]) * 1.4426950408889634f;
    float x = 0.f;
    for (int c = 0; c < NCHUNK; ++c) {
        x0[(size_t)c * BDN + gid] = x;
        float sdt = sumdt[(size_t)c * BD + bd];
        x = fmaf(exp2f(A2 * sdt), x, localx[(size_t)c * BDN + gid]);
    }
    carry[gid] = x;
}

// Pass C: re-scan each chunk from its true start state, emit y.
__device__ __forceinline__ void loadC4(const unsigned short* __restrict__ ub,
                                       const unsigned short* __restrict__ dtp,
                                       const unsigned short* __restrict__ btp,
                                       const unsigned short* __restrict__ ctp,
                                       size_t base, int l0,
                                       float (&T)[4], float (&U)[4],
                                       float (&Bv)[4], float (&Cv)[4]) {
#pragma unroll
    for (int i = 0; i < 4; ++i) {
        size_t off = base + (size_t)(l0 + i) * D_IN;
        T[i] = bf2f(dtp[off]);
        U[i] = bf2f(ub[off]);
        Bv[i] = bf2f(btp[off]);
        Cv[i] = bf2f(ctp[off]);
    }
}

__device__ __forceinline__ void compC4(float (&x)[16],
                                       const float (&A2)[16], const float (&Bb)[16],
                                       const float (&Cb)[16], float Dd,
                                       float* __restrict__ y, size_t base, int l0,
                                       const float (&T)[4], const float (&U)[4],
                                       const float (&Bv)[4], const float (&Cv)[4]) {
#pragma unroll
    for (int i = 0; i < 4; ++i) {
        float dtv = T[i], uv = U[i];
        float s = dtv * Bv[i] * uv;
        float y0 = 0.f, y1 = 0.f, y2 = 0.f, y3 = 0.f;
#pragma unroll
        for (int n = 0; n < 16; n += 4) {
            x[n]     = fmaf(exp2f(A2[n] * dtv),     x[n],     s * Bb[n]);
            y0 = fmaf(Cb[n], x[n], y0);
            x[n + 1] = fmaf(exp2f(A2[n + 1] * dtv), x[n + 1], s * Bb[n + 1]);
            y1 = fmaf(Cb[n + 1], x[n + 1], y1);
            x[n + 2] = fmaf(exp2f(A2[n + 2] * dtv), x[n + 2], s * Bb[n + 2]);
            y2 = fmaf(Cb[n + 2], x[n + 2], y2);
            x[n + 3] = fmaf(exp2f(A2[n + 3] * dtv), x[n + 3], s * Bb[n + 3]);
            y3 = fmaf(Cb[n + 3], x[n + 3], y3);
        }
        y[base + (size_t)(l0 + i) * D_IN] = fmaf(Dd, uv, Cv[i] * ((y0 + y1) + (y2 + y3)));
    }
}

__global__ __launch_bounds__(256) void k_scanC(const unsigned short* __restrict__ ub,
                                               const unsigned short* __restrict__ dtp,
                                               const unsigned short* __restrict__ btp,
                                               const unsigned short* __restrict__ ctp,
                                               const float* __restrict__ a_raw,
                                               const float* __restrict__ Bbp,
                                               const float* __restrict__ Cbp,
                                               const float* __restrict__ Dv,
                                               const float* __restrict__ x0,
                                               float* __restrict__ y) {
    int tid = threadIdx.x;
    int d = blockIdx.x * 256 + tid;
    int c = blockIdx.y, b = blockIdx.z;
    const float L2E = 1.4426950408889634f;

    float A2[16], Bb[16], Cb[16];
#pragma unroll
    for (int n = 0; n < 16; n += 4) {
        f32x4 a = *(const f32x4*)(a_raw + d * STATE_N + n);
        f32x4 bv = *(const f32x4*)(Bbp + d * STATE_N + n);
        f32x4 cv = *(const f32x4*)(Cbp + d * STATE_N + n);
#pragma unroll
        for (int j = 0; j < 4; ++j) {
            A2[n + j] = -softplus_f(a[j]) * L2E;
            Bb[n + j] = bv[j];
            Cb[n + j] = cv[j];
        }
    }
    float Dd = Dv[d];

    float x[16];
    size_t xb = (size_t)c * BDN + ((size_t)b * D_IN + d) * STATE_N;
#pragma unroll
    for (int n = 0; n < 16; n += 4) {
        f32x4 v = *(const f32x4*)(x0 + xb + n);
        x[n] = v[0]; x[n + 1] = v[1]; x[n + 2] = v[2]; x[n + 3] = v[3];
    }

    size_t base = ((size_t)b * SEQ_L + (size_t)c * LC) * D_IN + d;
    float tA[4], uA[4], bA[4], cA[4], tB[4], uB[4], bB[4], cB[4];
    loadC4(ub, dtp, btp, ctp, base, 0, tA, uA, bA, cA);
    for (int l0 = 0; l0 < LC; l0 += 8) {
        loadC4(ub, dtp, btp, ctp, base, l0 + 4, tB, uB, bB, cB);
        compC4(x, A2, Bb, Cb, Dd, y, base, l0, tA, uA, bA, cA);
        if (l0 + 8 < LC)
            loadC4(ub, dtp, btp, ctp, base, l0 + 8, tA, uA, bA, cA);
        compC4(x, A2, Bb, Cb, Dd, y, base, l0 + 4, tB, uB, bB, cB);
    }
}

// ---------------- launch ----------------
extern "C" void kernel_launch(void* const* d_in, const int* in_sizes, int n_in,
                              void* d_out, int out_size, void* d_ws, size_t ws_size,
                              hipStream_t stream) {
    const float* u     = (const float*)d_in[0];
    const float* Wdt   = (const float*)d_in[1];
    const float* bdt   = (const float*)d_in[2];
    const float* Wb    = (const float*)d_in[3];
    const float* bb    = (const float*)d_in[4];
    const float* Wc    = (const float*)d_in[5];
    const float* bc    = (const float*)d_in[6];
    const float* a_raw = (const float*)d_in[7];
    const float* Bbp   = (const float*)d_in[8];
    const float* Cbp   = (const float*)d_in[9];
    const float* Dv    = (const float*)d_in[10];

    float* out = (float*)d_out;
    float* carry = out;                                      // (B, d, N)
    float* y = out + (size_t)BATCH * D_IN * STATE_N;         // (B, L, d)

    const size_t Mel = (size_t)M_TOT * D_IN;                 // 33.5M elements
    char* ws = (char*)d_ws;
    unsigned short* ub  = (unsigned short*)ws;                          // Mel*2
    unsigned short* Btb = (unsigned short*)(ws + Mel * 2);              // NCAT*D_IN*2
    char* p = ws + Mel * 2 + (size_t)NCAT * D_IN * 2;
    unsigned short* dtp = (unsigned short*)p;                           // Mel*2
    unsigned short* btp = (unsigned short*)(p + Mel * 2);               // Mel*2
    unsigned short* ctp = (unsigned short*)(p + Mel * 4);               // Mel*2
    char* q = p + Mel * 6;
    float* localx = (float*)q;                                          // NCHUNK*BDN*4
    float* x0v    = (float*)(q + (size_t)NCHUNK * BDN * 4);             // NCHUNK*BDN*4
    float* sumdt  = (float*)(q + (size_t)NCHUNK * BDN * 8);             // NCHUNK*BD*4

    k_cvt_u<<<dim3((M_TOT * D_IN) / (256 * 8)), dim3(256), 0, stream>>>(u, ub);
    k_transpose<<<dim3(NCAT / 32, D_IN / 32), dim3(32, 8), 0, stream>>>(Wdt, Wb, Wc, Btb);
    k_gemm<<<dim3((M_TOT / 128) * (NCAT / 128)), dim3(256), 0, stream>>>(ub, Btb, bdt, bb, bc,
                                                                         dtp, btp, ctp);
    k_scanA<<<dim3(D_IN / 256, NCHUNK, BATCH), dim3(256), 0, stream>>>(ub, dtp, btp, a_raw,
                                                                       Bbp, localx, sumdt);
    k_scanB<<<dim3(BDN / 256), dim3(256), 0, stream>>>(localx, sumdt, a_raw, x0v, carry);
    k_scanC<<<dim3(D_IN / 256, NCHUNK, BATCH), dim3(256), 0, stream>>>(ub, dtp, btp, ctp,
                                                                       a_raw, Bbp, Cbp, Dv,
                                                                       x0v, y);
}